// Round 6
// baseline (147.935 us; speedup 1.0000x reference)
//
#include <hip/hip_runtime.h>

// QRNN: SEQ=4096, BATCH=8, CIN=256, HID=256, K=2 (lookback=1)
// R8: gemm blocks compute Z AND F for a 64-row x 64-col patch (same FLOPs/LDS/
//     VGPR as R7's 64x128 single-matrix block) -> epilogue emits per-8-step scan
//     partials (Ac/Cc, NCHUNK=512) from the rounded bf16 values => scanA DELETED.
//     scanB: 8 chunks/lane serial + 64-lane Hillis-Steele. scanC: CHUNK=8 replay.
//     ws is 256MiB (fill evidence) -> Ac/Cc/Hs live past Xbf, no aliasing games.
//
// ws: zbf 16MB | fbf 16MB | Xbf 16.8MB | Bm 0.5MB | Ac 4MB@50MiB | Cc 4MB@54MiB | Hs 4MB@58MiB

#define SEQn 4096
#define NCH 2048          // BATCH*HID channels
#define CHUNK 8
#define NCHUNK 512

typedef __attribute__((ext_vector_type(8))) short bf16x8;
typedef __attribute__((ext_vector_type(4))) float floatx4;

__device__ __forceinline__ unsigned short f2bf(float x) {
  unsigned int u = __float_as_uint(x);
  u += 0x7fffu + ((u >> 16) & 1u);     // RNE
  return (unsigned short)(u >> 16);
}
__device__ __forceinline__ float bf2f(ushort u) {
  return __uint_as_float((unsigned int)u << 16);
}
__device__ __forceinline__ float sigf(float x) {
  return __builtin_amdgcn_rcpf(1.0f + __expf(-x));
}

// ---- 1) merged pack: blocks [0,1024) pack W, blocks [1024,9218) pack X ----
__global__ void pack_kernel(const float* __restrict__ X,
                            const float* __restrict__ Wz, const float* __restrict__ Wf,
                            ushort* __restrict__ Xbf, ushort* __restrict__ Bm) {
  if (blockIdx.x < 1024) {
    int idx = blockIdx.x * 256 + threadIdx.x;        // 0..262143
    int n = idx >> 9, kin = idx & 511;
    const float* W = (n < 256) ? Wz : Wf;
    int h = n & 255, c = kin & 255, tap = kin >> 8;  // kin<256: tap0 (X[s-1])
    Bm[idx] = f2bf(W[h * 512 + c * 2 + tap]);
  } else {
    int idx = (blockIdx.x - 1024) * 256 + threadIdx.x;
    const int total4 = ((SEQn + 1) * NCH) / 4;       // 2,097,664
    if (idx >= total4) return;
    const int pad4 = NCH / 4;
    float4 v;
    if (idx < pad4) { v.x = 0.f; v.y = 0.f; v.z = 0.f; v.w = 0.f; }
    else v = ((const float4*)X)[idx - pad4];
    ushort4 o;
    o.x = f2bf(v.x); o.y = f2bf(v.y); o.z = f2bf(v.z); o.w = f2bf(v.w);
    ((ushort4*)Xbf)[idx] = o;
  }
}

// ---- 2) GEMM 64 rows x 64 cols x {Z,F}, BK=64, mfma_f32_16x16x32_bf16 ----
// LDS seg (row, s) holds global k-seg s^(row&7)  (seg = 16B = 8 bf16)
// sB rows 0..63 = Wz panel (cols ncol0..+64), rows 64..127 = Wf panel.
__global__ __launch_bounds__(256) void gemm_kernel(
    const ushort* __restrict__ Xbf, const ushort* __restrict__ Bm,
    const float* __restrict__ bz, const float* __restrict__ bfb,
    ushort* __restrict__ zout, ushort* __restrict__ fout,
    float* __restrict__ Ac, float* __restrict__ Cc) {
  __shared__ __align__(16) char smem_raw[24576];
  ushort* sA = (ushort*)smem_raw;                 // 64 rows x 64 k   (8KB)
  ushort* sB = sA + 4096;                         // 128 rows x 64 k  (16KB)

  const int tid  = threadIdx.x;
  const int wave = tid >> 6;
  const int lane = tid & 63;
  const int quad = lane >> 4;
  const int lrow = lane & 15;
  const int wm = wave >> 1;          // row half (32 rows)
  const int wn = wave & 1;           // col half (32 cols)
  const int bm = blockIdx.x;         // 0..511 (8 seq positions each)
  const int bn = blockIdx.y;         // 0..3 col quarter (64 h each)
  const int ncol0 = bn * 64;

  floatx4 acc[2][2][2];              // [zf][fi][fj]
#pragma unroll
  for (int zf = 0; zf < 2; ++zf)
#pragma unroll
    for (int i = 0; i < 2; ++i)
#pragma unroll
      for (int j = 0; j < 2; ++j)
        acc[zf][i][j] = (floatx4){0.f, 0.f, 0.f, 0.f};

  // staging coords: A 2 segs/thread (512 segs), B 4 segs/thread (1024 segs)
  int rowA[2], gkoA[2], rowBG[4], gkoB[4];
#pragma unroll
  for (int it = 0; it < 2; ++it) {
    int g = it * 256 + wave * 64 + lane;     // 0..511
    int row = g >> 3, s = g & 7;
    rowA[it] = row;                          // 0..63
    gkoA[it] = (s ^ (row & 7)) * 8;
  }
#pragma unroll
  for (int it = 0; it < 4; ++it) {
    int g = it * 256 + wave * 64 + lane;     // 0..1023
    int row = g >> 3, s = g & 7;             // LDS row 0..127
    rowBG[it] = (row < 64) ? (ncol0 + row) : (192 + ncol0 + row);  // Wz / Wf panels
    gkoB[it] = (s ^ (row & 7)) * 8;
  }
  char* ldsA = smem_raw + wave * 1024 + (lane << 4);
  char* ldsB = smem_raw + 8192 + wave * 1024 + (lane << 4);

  const ushort* Arow = Xbf + (size_t)(bm * 64) * 256;

  for (int k0 = 0; k0 < 512; k0 += 64) {
    __syncthreads();                 // prev iter ds_reads done
#pragma unroll
    for (int it = 0; it < 2; ++it) {
      const int kk = k0 + gkoA[it];
      const int cA = (kk < 256) ? kk : kk + 1792;     // tap1 lives +2048-256
      __builtin_amdgcn_global_load_lds(
          (const __attribute__((address_space(1))) void*)(Arow + (size_t)rowA[it] * 256 + cA),
          (__attribute__((address_space(3))) void*)(ldsA + it * 4096), 16, 0, 0);
    }
#pragma unroll
    for (int it = 0; it < 4; ++it) {
      const int kk = k0 + gkoB[it];
      __builtin_amdgcn_global_load_lds(
          (const __attribute__((address_space(1))) void*)(Bm + (size_t)rowBG[it] * 512 + kk),
          (__attribute__((address_space(3))) void*)(ldsB + it * 4096), 16, 0, 0);
    }
    __syncthreads();

    bf16x8 af[2][2];
#pragma unroll
    for (int fi = 0; fi < 2; ++fi) {
      const int r = wm * 32 + fi * 16 + lrow;
#pragma unroll
      for (int ks = 0; ks < 2; ++ks) {
        const int s = (ks * 4 + quad) ^ (r & 7);
        af[fi][ks] = *(const bf16x8*)&sA[r * 64 + s * 8];
      }
    }
#pragma unroll
    for (int zf = 0; zf < 2; ++zf) {
      bf16x8 bfr[2][2];
#pragma unroll
      for (int fj = 0; fj < 2; ++fj) {
        const int r = zf * 64 + wn * 32 + fj * 16 + lrow;
#pragma unroll
        for (int ks = 0; ks < 2; ++ks) {
          const int s = (ks * 4 + quad) ^ (r & 7);
          bfr[fj][ks] = *(const bf16x8*)&sB[r * 64 + s * 8];
        }
      }
#pragma unroll
      for (int ks = 0; ks < 2; ++ks)
#pragma unroll
        for (int fi = 0; fi < 2; ++fi)
#pragma unroll
          for (int fj = 0; fj < 2; ++fj)
            acc[zf][fi][fj] = __builtin_amdgcn_mfma_f32_16x16x32_bf16(af[fi][ks], bfr[fj][ks], acc[zf][fi][fj], 0, 0, 0);
    }
  }

  // ---- epilogue: activations -> bf16 tiles in LDS, chunk partials, global writes
  float bvz[2], bvf[2];
#pragma unroll
  for (int fj = 0; fj < 2; ++fj) {
    bvz[fj] = bz[ncol0 + wn * 32 + fj * 16 + lrow];
    bvf[fj] = bfb[ncol0 + wn * 32 + fj * 16 + lrow];
  }

  __syncthreads();                   // all ds_reads of sA/sB done (tiles alias)
  ushort* sTz = (ushort*)smem_raw;   // 64 x 72  (9216 B)
  ushort* sTf = sTz + 64 * 72;       // 64 x 72  (9216 B)
#pragma unroll
  for (int fi = 0; fi < 2; ++fi)
#pragma unroll
    for (int fj = 0; fj < 2; ++fj)
#pragma unroll
      for (int r = 0; r < 4; ++r) {
        int row = wm * 32 + fi * 16 + quad * 4 + r;
        int col = wn * 32 + fj * 16 + lrow;
        float vz = acc[0][fi][fj][r] + bvz[fj];
        float vf = acc[1][fi][fj][r] + bvf[fj];
        sTz[row * 72 + col] = f2bf(vz * sigf(1.702f * vz));   // QuickGELU
        sTf[row * 72 + col] = f2bf(sigf(vf));                 // sigmoid
      }
  __syncthreads();

  // per-channel 8-step partials from rounded bf16 (identical math to old scanA)
#pragma unroll
  for (int half = 0; half < 2; ++half) {
    int cl = tid + half * 256;       // 0..511 = b*64 + h
    int b = cl >> 6, h = cl & 63;
    float A = 1.f, C = 0.f;
#pragma unroll
    for (int i = 0; i < 8; ++i) {
      float zv = bf2f(sTz[(i * 8 + b) * 72 + h]);
      float fv = bf2f(sTf[(i * 8 + b) * 72 + h]);
      float a = 1.f - fv;
      C = fmaf(a, C, fv * zv); A *= a;
    }
    size_t o = (size_t)bm * NCH + b * 256 + ncol0 + h;
    Ac[o] = A; Cc[o] = C;
  }

  // z/f bf16 tiles -> global (coalesced 16B segs)
#pragma unroll
  for (int it = 0; it < 2; ++it) {
    int e = tid + it * 256;          // 512 segs = 64 rows x 8 segs
    int row = e >> 3, s8 = e & 7;
    uint4 vz = *(uint4*)&sTz[row * 72 + s8 * 8];
    uint4 vf = *(uint4*)&sTf[row * 72 + s8 * 8];
    size_t o = (size_t)(bm * 64 + row) * 256 + ncol0 + s8 * 8;
    *(uint4*)(zout + o) = vz;
    *(uint4*)(fout + o) = vf;
  }
}

// ---- 3) cross-chunk scan: one wave per channel; 8 chunks/lane + Hillis-Steele ----
__global__ void scanB_kernel(const float* __restrict__ hidden,
                             const float* __restrict__ Ac, const float* __restrict__ Cc,
                             float* __restrict__ Hs) {
  const int lane = threadIdx.x & 63;
  const int ch = blockIdx.x * 4 + (threadIdx.x >> 6);   // 512 blocks x 4 waves
  float av[8], cv[8];
  float a = 1.f, c = 0.f;
#pragma unroll
  for (int i = 0; i < 8; ++i) {
    av[i] = a; cv[i] = c;            // exclusive prefix within lane
    int j = lane * 8 + i;
    float Aj = Ac[(size_t)j * NCH + ch];
    float Cj = Cc[(size_t)j * NCH + ch];
    c = fmaf(Aj, c, Cj);
    a *= Aj;
  }
#pragma unroll
  for (int d = 1; d < 64; d <<= 1) {
    float pa = __shfl_up(a, d, 64);
    float pc = __shfl_up(c, d, 64);
    if (lane >= d) { c = fmaf(a, pc, c); a *= pa; }
  }
  float xa = __shfl_up(a, 1, 64), xc = __shfl_up(c, 1, 64);
  if (lane == 0) { xa = 1.f; xc = 0.f; }
  float h0 = hidden[ch];
  float hs = fmaf(xa, h0, xc);       // h at start of chunk lane*8
#pragma unroll
  for (int i = 0; i < 8; ++i)
    Hs[(size_t)(lane * 8 + i) * NCH + ch] = fmaf(av[i], hs, cv[i]);
}

// ---- 4) replay within 8-step chunk, 2 channels/thread, fp32 out ----
__global__ void scanC_kernel(const ushort* __restrict__ z, const ushort* __restrict__ f,
                             const float* __restrict__ Hs, float* __restrict__ out) {
  int t = blockIdx.x * blockDim.x + threadIdx.x;   // 0..524287
  int ch2 = t & 1023;
  int j = t >> 10;                                  // chunk 0..511
  float2 hv = *(const float2*)(Hs + (size_t)j * NCH + 2 * ch2);
  float h0 = hv.x, h1 = hv.y;
  const size_t base = (size_t)j * CHUNK * NCH + 2 * ch2;
  const ushort* zp = z + base;
  const ushort* fp = f + base;
  float* op = out + base;
#pragma unroll
  for (int i = 0; i < CHUNK; ++i) {
    ushort2 fv = *(const ushort2*)(fp + (size_t)i * NCH);
    ushort2 zv = *(const ushort2*)(zp + (size_t)i * NCH);
    float f0 = bf2f(fv.x), f1 = bf2f(fv.y);
    h0 = fmaf(f0, bf2f(zv.x) - h0, h0);
    h1 = fmaf(f1, bf2f(zv.y) - h1, h1);
    float2 o = {h0, h1};
    *(float2*)(op + (size_t)i * NCH) = o;
  }
  if (j == NCHUNK - 1) {
    float2 o = {h0, h1};
    *(float2*)(out + (size_t)SEQn * NCH + 2 * ch2) = o;   // h_last row
  }
}

extern "C" void kernel_launch(void* const* d_in, const int* in_sizes, int n_in,
                              void* d_out, int out_size, void* d_ws, size_t ws_size,
                              hipStream_t stream) {
  const float* X      = (const float*)d_in[0];
  const float* hidden = (const float*)d_in[1];
  const float* Wz     = (const float*)d_in[2];
  const float* bz     = (const float*)d_in[3];
  const float* Wf     = (const float*)d_in[4];
  const float* bfb    = (const float*)d_in[5];
  float* out = (float*)d_out;

  char* ws = (char*)d_ws;
  ushort* zbf = (ushort*)ws;                       // 16,777,216 B
  ushort* fbf = (ushort*)(ws + 16777216);          // 16,777,216 B
  ushort* Xbf = (ushort*)(ws + 33554432);          // 16,781,312 B
  ushort* Bm  = (ushort*)(ws + 50335744);          //    524,288 B
  float* Ac = (float*)(ws + 52428800);             // 4 MB (512 x 2048)
  float* Cc = (float*)(ws + 56623104);             // 4 MB
  float* Hs = (float*)(ws + 60817408);             // 4 MB

  pack_kernel<<<9218, 256, 0, stream>>>(X, Wz, Wf, Xbf, Bm);
  dim3 ggrid(512, 4);
  gemm_kernel<<<ggrid, 256, 0, stream>>>(Xbf, Bm, bz, bfb, zbf, fbf, Ac, Cc);
  scanB_kernel<<<512, 256, 0, stream>>>(hidden, Ac, Cc, Hs);
  scanC_kernel<<<2048, 256, 0, stream>>>(zbf, fbf, Hs, out);
}

// Round 7
// 137.961 us; speedup vs baseline: 1.0723x; 1.0723x over previous
//
#include <hip/hip_runtime.h>

// QRNN: SEQ=4096, BATCH=8, CIN=256, HID=256, K=2 (lookback=1)
// R9: R7 (verified best, 139.5us) + XCD-aware gemm dispatch: 1D grid 2048,
//     decode so the 4 bn-blocks sharing an A-panel (same bm) land on the SAME
//     XCD (same id mod 8) adjacently in time -> A-panel read once from HBM,
//     3x from L2. R8's epilogue-fused scan partials reverted (+8.4us regression).
//
// ws: zbf 16MB | fbf 16MB | Xbf 16MB (dead after gemm; Ac/Cc/Hs aliased) | Bm 0.5MB

#define SEQn 4096
#define NCH 2048          // BATCH*HID channels
#define CHUNK 32
#define NCHUNK 128

typedef __attribute__((ext_vector_type(8))) short bf16x8;
typedef __attribute__((ext_vector_type(4))) float floatx4;

__device__ __forceinline__ unsigned short f2bf(float x) {
  unsigned int u = __float_as_uint(x);
  u += 0x7fffu + ((u >> 16) & 1u);     // RNE
  return (unsigned short)(u >> 16);
}
__device__ __forceinline__ float bf2f(ushort u) {
  return __uint_as_float((unsigned int)u << 16);
}
__device__ __forceinline__ float sigf(float x) {
  return __builtin_amdgcn_rcpf(1.0f + __expf(-x));
}

// ---- 1) merged pack: blocks [0,1024) pack W, blocks [1024,9218) pack X ----
__global__ void pack_kernel(const float* __restrict__ X,
                            const float* __restrict__ Wz, const float* __restrict__ Wf,
                            ushort* __restrict__ Xbf, ushort* __restrict__ Bm) {
  if (blockIdx.x < 1024) {
    int idx = blockIdx.x * 256 + threadIdx.x;        // 0..262143
    int n = idx >> 9, kin = idx & 511;
    const float* W = (n < 256) ? Wz : Wf;
    int h = n & 255, c = kin & 255, tap = kin >> 8;  // kin<256: tap0 (X[s-1])
    Bm[idx] = f2bf(W[h * 512 + c * 2 + tap]);
  } else {
    int idx = (blockIdx.x - 1024) * 256 + threadIdx.x;
    const int total4 = ((SEQn + 1) * NCH) / 4;       // 2,097,664
    if (idx >= total4) return;
    const int pad4 = NCH / 4;
    float4 v;
    if (idx < pad4) { v.x = 0.f; v.y = 0.f; v.z = 0.f; v.w = 0.f; }
    else v = ((const float4*)X)[idx - pad4];
    ushort4 o;
    o.x = f2bf(v.x); o.y = f2bf(v.y); o.z = f2bf(v.z); o.w = f2bf(v.w);
    ((ushort4*)Xbf)[idx] = o;
  }
}

// ---- 2) GEMM 64x128, BK=64, mfma_f32_16x16x32_bf16, swizzled LDS ----
// LDS seg (row, s) holds global k-seg s^(row&7)  (seg = 16B = 8 bf16)
// 1D grid 2048: xcd=id&7, bn=(id>>3)&3, bm=((id>>5)<<3)|xcd  -> A-panel sharers
// (same bm, 4 bn) have same id%8 => same XCD L2, adjacent dispatch time.
__global__ __launch_bounds__(256) void gemm_kernel(
    const ushort* __restrict__ Xbf, const ushort* __restrict__ Bm,
    const float* __restrict__ bz, const float* __restrict__ bfb,
    ushort* __restrict__ zout, ushort* __restrict__ fout) {
  __shared__ __align__(16) char smem_raw[24576];
  ushort* sA = (ushort*)smem_raw;                 // 64 rows x 64 k   (8KB)
  ushort* sB = sA + 4096;                         // 128 cols x 64 k  (16KB)
  ushort* sT = (ushort*)smem_raw;                 // epilogue 64 x 136 (17.4KB)

  const int tid  = threadIdx.x;
  const int wave = tid >> 6;
  const int lane = tid & 63;
  const int quad = lane >> 4;
  const int lrow = lane & 15;
  const int wm = wave >> 1;          // 2x2 wave grid, each 32x64 output
  const int wn = wave & 1;
  const int id = blockIdx.x;         // 0..2047
  const int bn = (id >> 3) & 3;      // 0..3 (0,1=Z; 2,3=F)
  const int bm = ((id >> 5) << 3) | (id & 7);   // 0..511

  floatx4 acc[2][4];
#pragma unroll
  for (int i = 0; i < 2; ++i)
#pragma unroll
    for (int j = 0; j < 4; ++j)
      acc[i][j] = (floatx4){0.f, 0.f, 0.f, 0.f};

  // staging coords: A 2 segs/thread (512 segs), B 4 segs/thread (1024 segs)
  int rowA[2], gkoA[2], rowB[4], gkoB[4];
#pragma unroll
  for (int it = 0; it < 2; ++it) {
    int g = it * 256 + wave * 64 + lane;     // 0..511
    int row = g >> 3, s = g & 7;
    rowA[it] = row;                          // 0..63
    gkoA[it] = (s ^ (row & 7)) * 8;
  }
#pragma unroll
  for (int it = 0; it < 4; ++it) {
    int g = it * 256 + wave * 64 + lane;     // 0..1023
    int row = g >> 3, s = g & 7;
    rowB[it] = row;                          // 0..127
    gkoB[it] = (s ^ (row & 7)) * 8;
  }
  char* ldsA = smem_raw + wave * 1024 + (lane << 4);
  char* ldsB = smem_raw + 8192 + wave * 1024 + (lane << 4);

  const ushort* Arow = Xbf + (size_t)(bm * 64) * 256;
  const ushort* Brow = Bm + (size_t)(bn * 128) * 512;

  for (int k0 = 0; k0 < 512; k0 += 64) {
    __syncthreads();                 // prev iter ds_reads done
#pragma unroll
    for (int it = 0; it < 2; ++it) {
      const int kk = k0 + gkoA[it];
      const int cA = (kk < 256) ? kk : kk + 1792;     // tap1 lives +2048-256
      __builtin_amdgcn_global_load_lds(
          (const __attribute__((address_space(1))) void*)(Arow + (size_t)rowA[it] * 256 + cA),
          (__attribute__((address_space(3))) void*)(ldsA + it * 4096), 16, 0, 0);
    }
#pragma unroll
    for (int it = 0; it < 4; ++it) {
      const int kk = k0 + gkoB[it];
      __builtin_amdgcn_global_load_lds(
          (const __attribute__((address_space(1))) void*)(Brow + (size_t)rowB[it] * 512 + kk),
          (__attribute__((address_space(3))) void*)(ldsB + it * 4096), 16, 0, 0);
    }
    __syncthreads();

    bf16x8 af[2][2], bfr[4][2];
#pragma unroll
    for (int fi = 0; fi < 2; ++fi) {
      const int r = wm * 32 + fi * 16 + lrow;
#pragma unroll
      for (int ks = 0; ks < 2; ++ks) {
        const int s = (ks * 4 + quad) ^ (r & 7);
        af[fi][ks] = *(const bf16x8*)&sA[r * 64 + s * 8];
      }
    }
#pragma unroll
    for (int fj = 0; fj < 4; ++fj) {
      const int r = wn * 64 + fj * 16 + lrow;
#pragma unroll
      for (int ks = 0; ks < 2; ++ks) {
        const int s = (ks * 4 + quad) ^ (r & 7);
        bfr[fj][ks] = *(const bf16x8*)&sB[r * 64 + s * 8];
      }
    }
#pragma unroll
    for (int ks = 0; ks < 2; ++ks)
#pragma unroll
      for (int fi = 0; fi < 2; ++fi)
#pragma unroll
        for (int fj = 0; fj < 4; ++fj)
          acc[fi][fj] = __builtin_amdgcn_mfma_f32_16x16x32_bf16(af[fi][ks], bfr[fj][ks], acc[fi][fj], 0, 0, 0);
  }

  // epilogue: activation -> bf16 -> sT (64 x 136 padded) -> coalesced dwordx4
  const bool isZ = (bn < 2);
  ushort* gout = isZ ? zout : fout;
  const int ncol0 = (bn & 1) * 128;
  const float* bias = isZ ? bz : bfb;
  float bv[4];
#pragma unroll
  for (int fj = 0; fj < 4; ++fj)
    bv[fj] = bias[ncol0 + wn * 64 + fj * 16 + lrow];

  __syncthreads();                   // all ds_reads of sA/sB done (sT aliases)
#pragma unroll
  for (int fi = 0; fi < 2; ++fi)
#pragma unroll
    for (int fj = 0; fj < 4; ++fj)
#pragma unroll
      for (int r = 0; r < 4; ++r) {
        float v = acc[fi][fj][r] + bv[fj];
        float o = isZ ? (v * sigf(1.702f * v)) : sigf(v);
        sT[(wm * 32 + fi * 16 + quad * 4 + r) * 136 + wn * 64 + fj * 16 + lrow] = f2bf(o);
      }
  __syncthreads();
#pragma unroll
  for (int it = 0; it < 4; ++it) {
    int e = tid + it * 256;           // 1024 segs = 64 rows x 16 segs
    int row = e >> 4, seg = e & 15;
    uint4 v = *(uint4*)&sT[row * 136 + seg * 8];
    *(uint4*)(gout + (size_t)(bm * 64 + row) * 256 + ncol0 + seg * 8) = v;
  }
}

// ---- 3) per-chunk reduction, 2 channels/thread ----
__global__ void scanA_kernel(const ushort* __restrict__ z, const ushort* __restrict__ f,
                             float* __restrict__ Ac, float* __restrict__ Cc) {
  int t = blockIdx.x * blockDim.x + threadIdx.x;   // 0..131071
  int ch2 = t & 1023;
  int j = t >> 10;                                  // 0..127
  const size_t base = (size_t)j * CHUNK * NCH + 2 * ch2;
  const ushort* zp = z + base;
  const ushort* fp = f + base;
  float A0 = 1.0f, C0 = 0.0f, A1 = 1.0f, C1 = 0.0f;
#pragma unroll
  for (int i = 0; i < CHUNK; ++i) {
    ushort2 fv = *(const ushort2*)(fp + (size_t)i * NCH);
    ushort2 zv = *(const ushort2*)(zp + (size_t)i * NCH);
    float f0 = bf2f(fv.x), f1 = bf2f(fv.y);
    float a0 = 1.0f - f0, a1 = 1.0f - f1;
    C0 = fmaf(a0, C0, f0 * bf2f(zv.x)); A0 *= a0;
    C1 = fmaf(a1, C1, f1 * bf2f(zv.y)); A1 *= a1;
  }
  float2 Av = {A0, A1}, Cv = {C0, C1};
  *(float2*)(Ac + (size_t)j * NCH + 2 * ch2) = Av;
  *(float2*)(Cc + (size_t)j * NCH + 2 * ch2) = Cv;
}

// ---- 4) cross-chunk scan: one wave per channel, shfl Hillis-Steele ----
__global__ void scanB_kernel(const float* __restrict__ hidden,
                             const float* __restrict__ Ac, const float* __restrict__ Cc,
                             float* __restrict__ Hs) {
  const int lane = threadIdx.x & 63;
  const int ch = blockIdx.x * 4 + (threadIdx.x >> 6);   // 512 blocks x 4 waves
  const int j0 = 2 * lane, j1 = 2 * lane + 1;
  float a0 = Ac[j0 * NCH + ch], c0 = Cc[j0 * NCH + ch];
  float a1 = Ac[j1 * NCH + ch], c1 = Cc[j1 * NCH + ch];
  float a = a0 * a1;
  float c = fmaf(a1, c0, c1);
#pragma unroll
  for (int d = 1; d < 64; d <<= 1) {
    float pa = __shfl_up(a, d, 64);
    float pc = __shfl_up(c, d, 64);
    if (lane >= d) { c = fmaf(a, pc, c); a *= pa; }
  }
  float xa = __shfl_up(a, 1, 64), xc = __shfl_up(c, 1, 64);
  if (lane == 0) { xa = 1.0f; xc = 0.0f; }
  float h0 = hidden[ch];
  float hs0 = fmaf(xa, h0, xc);
  Hs[j0 * NCH + ch] = hs0;
  Hs[j1 * NCH + ch] = fmaf(a0, hs0, c0);
}

// ---- 5) replay within chunk, 2 channels/thread, fp32 out ----
__global__ void scanC_kernel(const ushort* __restrict__ z, const ushort* __restrict__ f,
                             const float* __restrict__ Hs, float* __restrict__ out) {
  int t = blockIdx.x * blockDim.x + threadIdx.x;   // 0..131071
  int ch2 = t & 1023;
  int j = t >> 10;
  float2 hv = *(const float2*)(Hs + (size_t)j * NCH + 2 * ch2);
  float h0 = hv.x, h1 = hv.y;
  const size_t base = (size_t)j * CHUNK * NCH + 2 * ch2;
  const ushort* zp = z + base;
  const ushort* fp = f + base;
  float* op = out + base;
#pragma unroll
  for (int i = 0; i < CHUNK; ++i) {
    ushort2 fv = *(const ushort2*)(fp + (size_t)i * NCH);
    ushort2 zv = *(const ushort2*)(zp + (size_t)i * NCH);
    float f0 = bf2f(fv.x), f1 = bf2f(fv.y);
    h0 = fmaf(f0, bf2f(zv.x) - h0, h0);
    h1 = fmaf(f1, bf2f(zv.y) - h1, h1);
    float2 o = {h0, h1};
    *(float2*)(op + (size_t)i * NCH) = o;
  }
  if (j == NCHUNK - 1) {
    float2 o = {h0, h1};
    *(float2*)(out + (size_t)SEQn * NCH + 2 * ch2) = o;   // h_last row
  }
}

extern "C" void kernel_launch(void* const* d_in, const int* in_sizes, int n_in,
                              void* d_out, int out_size, void* d_ws, size_t ws_size,
                              hipStream_t stream) {
  const float* X      = (const float*)d_in[0];
  const float* hidden = (const float*)d_in[1];
  const float* Wz     = (const float*)d_in[2];
  const float* bz     = (const float*)d_in[3];
  const float* Wf     = (const float*)d_in[4];
  const float* bfb    = (const float*)d_in[5];
  float* out = (float*)d_out;

  char* ws = (char*)d_ws;
  ushort* zbf = (ushort*)ws;                       // 16,777,216 B
  ushort* fbf = (ushort*)(ws + 16777216);          // 16,777,216 B
  ushort* Xbf = (ushort*)(ws + 33554432);          // 16,781,312 B (dead after gemm)
  ushort* Bm  = (ushort*)(ws + 50335744);          //    524,288 B
  // aliased over Xbf (used only after gemm completes):
  float* Ac = (float*)(ws + 33554432);
  float* Cc = (float*)(ws + 34603008);
  float* Hs = (float*)(ws + 35651584);

  pack_kernel<<<9218, 256, 0, stream>>>(X, Wz, Wf, Xbf, Bm);
  gemm_kernel<<<2048, 256, 0, stream>>>(Xbf, Bm, bz, bfb, zbf, fbf);
  scanA_kernel<<<512, 256, 0, stream>>>(zbf, fbf, Ac, Cc);
  scanB_kernel<<<512, 256, 0, stream>>>(hidden, Ac, Cc, Hs);
  scanC_kernel<<<512, 256, 0, stream>>>(zbf, fbf, Hs, out);
}